// Round 5
// baseline (239.885 us; speedup 1.0000x reference)
//
#include <hip/hip_runtime.h>
#include <hip/hip_bf16.h>
#include <stdint.h>

#define NROWS 8192
#define DDIM  256
#define SIGMA_INV 10.0f

#define BM 64
#define BN 64
#define NSPLIT 4
#define JCHUNK (NROWS / NSPLIT)   // 2048
#define NITER  (JCHUNK / BN)      // 32
#define PSTR   72                 // pl row stride in halfs (144B, 16B-aligned)
#define KCHB   1056               // DMA chunk pitch: 1024B payload + 32B pad -> conflict-free reads
#define TPITCH 257                // prep_k fp32 tile pitch (conflict-free transpose reads)

typedef __attribute__((ext_vector_type(8))) short bf16x8;
typedef __attribute__((ext_vector_type(4))) float f32x4;

__device__ inline unsigned short f2bf(float x) {
  __hip_bfloat16 h = __float2bfloat16(x);
  return *reinterpret_cast<unsigned short*>(&h);
}

__device__ inline void dma16(const void* g, void* l) {
  __builtin_amdgcn_global_load_lds(
      (const __attribute__((address_space(1))) unsigned int*)g,
      (__attribute__((address_space(3))) unsigned int*)l, 16, 0, 0);
}

// ---------------- prep_k: normalize -> embn, transpose -> vt, zero out/l_part ----
__global__ __launch_bounds__(256) void prep_k(const float* __restrict__ emb,
                                              unsigned short* __restrict__ embn,
                                              unsigned short* __restrict__ vt,
                                              float* __restrict__ out,
                                              float* __restrict__ l_part) {
  __shared__ float tile[64 * TPITCH];   // 65.8 KB
  __shared__ float nrm[64];
  const int t = threadIdx.x, tr = t >> 6, tc = t & 63;
  const int row0 = blockIdx.x * 64;

  // zero-init out (8MB/128 blocks = 64KB each) and l_part — replaces memsets
  {
    float4 z = {0.f, 0.f, 0.f, 0.f};
    float4* op = (float4*)(out + (size_t)blockIdx.x * 16384);
    for (int i = 0; i < 16; ++i) op[i * 256 + t] = z;
    if (blockIdx.x < 32) l_part[blockIdx.x * 256 + t] = 0.f;
  }

  // load 64x256 fp32 tile + per-row inverse norms (wave tr owns row i*4+tr each i)
  for (int i = 0; i < 16; ++i) {
    const int r = i * 4 + tr;
    float4 v = *(const float4*)(emb + (size_t)(row0 + r) * DDIM + tc * 4);
    tile[r * TPITCH + tc * 4 + 0] = v.x;
    tile[r * TPITCH + tc * 4 + 1] = v.y;
    tile[r * TPITCH + tc * 4 + 2] = v.z;
    tile[r * TPITCH + tc * 4 + 3] = v.w;
    float ss = v.x * v.x + v.y * v.y + v.z * v.z + v.w * v.w;
    for (int off = 32; off >= 1; off >>= 1) ss += __shfl_xor(ss, off);
    if (tc == 0) nrm[r] = 1.0f / fmaxf(sqrtf(ss), 1e-12f);  // matches clip(norm,1e-12)
  }
  __syncthreads();

  // embn = normalized rows, bf16
  for (int i = 0; i < 16; ++i) {
    const int r = i * 4 + tr;
    const float sc = nrm[r];
    ushort4 o;
    o.x = f2bf(tile[r * TPITCH + tc * 4 + 0] * sc);
    o.y = f2bf(tile[r * TPITCH + tc * 4 + 1] * sc);
    o.z = f2bf(tile[r * TPITCH + tc * 4 + 2] * sc);
    o.w = f2bf(tile[r * TPITCH + tc * 4 + 3] * sc);
    ((ushort4*)(embn + (size_t)(row0 + r) * DDIM))[tc] = o;
  }
  // vt = RAW emb transposed (V-operand of P.V is emb_org), bf16.
  // R4 BUG was i<16 here -> only d<64 written, vt[64:256] stayed poison.
  // Full range: i<64 covers d = 0..255 (4 waves x 64 iters).
  // read tile[tc*257 + d]: bank (tc+d)%32 -> 2-way over 64 lanes = free.
  for (int i = 0; i < 64; ++i) {
    const int d = i * 4 + tr;
    vt[(size_t)d * NROWS + row0 + tc] = f2bf(tile[tc * TPITCH + d]);
  }
}

// ---------------- F: fused  S=Qn.Knt -> exp -> O += P.V, row sums ----------------
// grid = 128 mblk x 4 chunks = 512 blocks (exactly 2/CU), 256 threads (2mg x 2dh)
// kn DOUBLE-buffered: DMA(it+1) issued right after B1 -> compiler's pre-B2
// vmcnt(0) drains it behind the whole G1+exp phase. vfrag prefetch post-B1
// (hidden behind G1).
__global__ __launch_bounds__(256, 2) void fused_k(
    const unsigned short* __restrict__ embn,  // [N][D] bf16
    const unsigned short* __restrict__ vt,    // [D][N] bf16
    float* __restrict__ out,                  // [N][D] fp32, pre-zeroed, atomic accum
    float* __restrict__ l_part)               // [N] fp32, pre-zeroed, atomic accum
{
  __shared__ char kn[2][32 * KCHB];           // 2 x 33 KB, padded DMA-staged K-tiles
  __shared__ unsigned short pl[BM * PSTR];    // 9 KB, P transit

  const int tid = threadIdx.x;
  const int w = tid >> 6, lane = tid & 63;
  const int mg = w >> 1, dh = w & 1;
  const int q = lane >> 4, c = lane & 15;
  const int chunk = blockIdx.x & 3;           // %8 XCD round-robin -> each XCD serves one 2MB slice
  const int mblk = blockIdx.x >> 2;
  const int row0 = mblk * BM + mg * 32;
  const size_t j0base = (size_t)chunk * JCHUNK;

  // Q fragments resident: A[m=lane&15][k=q*8+j]
  bf16x8 qa[2][8];
  for (int mt = 0; mt < 2; ++mt)
    for (int k = 0; k < 8; ++k)
      qa[mt][k] = *(const bf16x8*)(embn + (size_t)(row0 + mt * 16 + c) * DDIM + k * 32 + q * 8);

  f32x4 oacc[2][8];
  for (int mt = 0; mt < 2; ++mt)
    for (int u = 0; u < 8; ++u) oacc[mt][u] = {0.f, 0.f, 0.f, 0.f};
  float lacc[2][4] = {};

  // prologue: stage tile 0 -> buf 0
  {
    const char* src = (const char*)(embn + j0base * DDIM);
    for (int cc = 0; cc < 8; ++cc) {
      const int ch = w * 8 + cc;
      dma16(src + ch * 1024 + lane * 16, kn[0] + ch * KCHB + lane * 16);
    }
  }

  for (int it = 0; it < NITER; ++it) {
    const int buf = it & 1;
    const size_t j0 = j0base + (size_t)it * BN;
    __syncthreads();  // B1: pure sync; DMA(it) already drained at prev B2 (prologue DMA at first B2... covered: it=0 reads buf0 drained here via vmcnt(0))

    // issue DMA(it+1) -> other buffer: drained at B2, hidden behind G1+exp.
    if (it + 1 < NITER) {
      const char* src = (const char*)(embn + (j0 + BN) * DDIM);
      for (int cc = 0; cc < 8; ++cc) {
        const int ch = w * 8 + cc;
        dma16(src + ch * 1024 + lane * 16, kn[buf ^ 1] + ch * KCHB + lane * 16);
      }
    }

    // prefetch V frags for THIS iter: drained at B2, hidden behind G1
    bf16x8 vfrag[2][8];
    for (int kk = 0; kk < 2; ++kk)
      for (int u = 0; u < 8; ++u) {
        const int d = dh * 128 + u * 16 + c;
        vfrag[kk][u] = *(const bf16x8*)(vt + (size_t)d * NROWS + j0 + kk * 32 + q * 8);
      }

    // ---- G1: S[32x64] = Q . Kn^T from kn[buf] (padded pitch: conflict-free) ----
    f32x4 sacc[2][2];
    for (int mt = 0; mt < 2; ++mt)
      for (int nt = 0; nt < 2; ++nt) sacc[mt][nt] = {0.f, 0.f, 0.f, 0.f};
    const int rb0 = (dh * 16 + (c >> 1)) * KCHB + (c & 1) * 512;      // row dh*32+c
    const int rb1 = (dh * 16 + 8 + (c >> 1)) * KCHB + (c & 1) * 512;  // row dh*32+16+c
    for (int k = 0; k < 8; ++k) {
      bf16x8 b0 = *(const bf16x8*)(kn[buf] + rb0 + k * 64 + q * 16);
      bf16x8 b1 = *(const bf16x8*)(kn[buf] + rb1 + k * 64 + q * 16);
      for (int mt = 0; mt < 2; ++mt) {
        sacc[mt][0] = __builtin_amdgcn_mfma_f32_16x16x32_bf16(qa[mt][k], b0, sacc[mt][0], 0, 0, 0);
        sacc[mt][1] = __builtin_amdgcn_mfma_f32_16x16x32_bf16(qa[mt][k], b1, sacc[mt][1], 0, 0, 0);
      }
    }

    // exp (fixed shift 10: cos<=1 so logits<=10; softmax shift-invariant) + P + row sums
    for (int mt = 0; mt < 2; ++mt)
      for (int nt = 0; nt < 2; ++nt)
        for (int r = 0; r < 4; ++r) {
          const float p = __expf(fmaf(SIGMA_INV, sacc[mt][nt][r], -SIGMA_INV));
          lacc[mt][r] += p;
          // C/D layout: row = q*4+r, col = c
          pl[(mg * 32 + mt * 16 + q * 4 + r) * PSTR + dh * 32 + nt * 16 + c] = f2bf(p);
        }

    __syncthreads();  // B2: pl ready; drains vfrag + DMA(it+1)

    // ---- G2: O[32x128] += P[32x64] . V[64x128] — LDS + registers only ----
    for (int kk = 0; kk < 2; ++kk) {
      bf16x8 ap0 = *(const bf16x8*)(pl + (mg * 32 + c) * PSTR + kk * 32 + q * 8);
      bf16x8 ap1 = *(const bf16x8*)(pl + (mg * 32 + 16 + c) * PSTR + kk * 32 + q * 8);
      for (int u = 0; u < 8; ++u) {
        oacc[0][u] = __builtin_amdgcn_mfma_f32_16x16x32_bf16(ap0, vfrag[kk][u], oacc[0][u], 0, 0, 0);
        oacc[1][u] = __builtin_amdgcn_mfma_f32_16x16x32_bf16(ap1, vfrag[kk][u], oacc[1][u], 0, 0, 0);
      }
    }
  }

  // epilogue: row sums across the 16 c-lanes, then device atomics
  for (int mt = 0; mt < 2; ++mt)
    for (int r = 0; r < 4; ++r) {
      float s = lacc[mt][r];
      s += __shfl_xor(s, 1); s += __shfl_xor(s, 2);
      s += __shfl_xor(s, 4); s += __shfl_xor(s, 8);
      if (c == 0)
        atomicAdd(&l_part[row0 + mt * 16 + q * 4 + r], s);
    }
  for (int mt = 0; mt < 2; ++mt)
    for (int u = 0; u < 8; ++u)
      for (int r = 0; r < 4; ++r)
        atomicAdd(&out[(size_t)(row0 + mt * 16 + q * 4 + r) * DDIM + dh * 128 + u * 16 + c],
                  oacc[mt][u][r]);
}

// ---------------- K4: divide by row sums ----------------
__global__ __launch_bounds__(256) void finalize_k(float* __restrict__ out,
                                                  const float* __restrict__ l_part) {
  const int row = blockIdx.x, t = threadIdx.x;
  out[(size_t)row * DDIM + t] /= l_part[row];
}

extern "C" void kernel_launch(void* const* d_in, const int* in_sizes, int n_in,
                              void* d_out, int out_size, void* d_ws, size_t ws_size,
                              hipStream_t stream) {
  const float* emb = (const float*)d_in[0];
  float* out = (float*)d_out;
  char* ws = (char*)d_ws;
  // ws layout: embn 4MB | vt 4MB | l_part 32KB
  unsigned short* embn = (unsigned short*)ws;
  unsigned short* vt   = (unsigned short*)(ws + ((size_t)4 << 20));
  float* l_part        = (float*)(ws + ((size_t)8 << 20));

  prep_k<<<NROWS / 64, 256, 0, stream>>>(emb, embn, vt, out, l_part);
  fused_k<<<(NROWS / BM) * NSPLIT, 256, 0, stream>>>(embn, vt, out, l_part);
  finalize_k<<<NROWS, 256, 0, stream>>>(out, l_part);
}